// Round 2
// baseline (1933.083 us; speedup 1.0000x reference)
//
#include <hip/hip_runtime.h>
#include <hip/hip_bf16.h>

typedef short bf16x8 __attribute__((ext_vector_type(8)));
typedef float f32x4 __attribute__((ext_vector_type(4)));

__device__ __forceinline__ unsigned short f2bf(float f) {
  union { float f; unsigned u; } c; c.f = f;
  unsigned u = c.u;
  return (unsigned short)((u + 0x7fffu + ((u >> 16) & 1u)) >> 16);
}
__device__ __forceinline__ float bf2f(unsigned short h) {
  union { unsigned u; float f; } c; c.u = ((unsigned)h) << 16;
  return c.f;
}

#define GL_LDS16(gp, lp)                                                        \
  __builtin_amdgcn_global_load_lds(                                             \
      (const __attribute__((address_space(1))) void*)(const void*)(gp),         \
      (__attribute__((address_space(3))) void*)(void*)(lp), 16, 0, 0)

// ---------------------------------------------------------------------------
// C[m,n] = sum_k A[m,k] * B[n,k]  (+ bias[n])
// OUT==0: fp32, C[row*ldc+col]        OUT==1: bf16, C[row*ldc+col]
// OUT==2: bf16 transposed, C[col*ldc+row]
// sAz/sBz/sCz are per-blockIdx.z ELEMENT offsets (column offsets for split-K /
// per-head views; full-plane offsets for batched score/PV GEMMs).
// 128x128 tile, BK=32, 4 waves (2x2), 16x16x32 bf16 MFMA. All dims must be
// tile-aligned (M%128==0, N%128==0, K%32==0) -- true for every call here.
// ---------------------------------------------------------------------------
template <int OUT>
__global__ __launch_bounds__(256)
void gemm_bt(const unsigned short* __restrict__ A, int lda, long sAz,
             const unsigned short* __restrict__ B, int ldb, long sBz,
             void* __restrict__ Cout, int ldc, long sCz,
             const float* __restrict__ bias, int K)
{
  __shared__ unsigned short lA[128 * 32];
  __shared__ unsigned short lB[128 * 32];

  const int tid  = threadIdx.x;
  const int lane = tid & 63;
  const int wave = tid >> 6;
  const int m0 = blockIdx.y * 128;
  const int n0 = blockIdx.x * 128;

  A += (long)blockIdx.z * sAz;
  B += (long)blockIdx.z * sBz;

  // staging: thread t covers (row = t>>2 [+64], 16B chunk = t&3) of the
  // [128][32]-element (64 B/row) tile; LDS dest offset = t*16 B (linear in
  // lane => matches global_load_lds wave-uniform-base + lane*16 rule).
  const int srow = tid >> 2;
  const int scol = (tid & 3) * 8;
  const long ldaL = lda, ldbL = ldb;
  const unsigned short* Ag = A + (long)(m0 + srow) * ldaL + scol;
  const unsigned short* Bg = B + (long)(n0 + srow) * ldbL + scol;
  unsigned short* lAp = &lA[tid * 8];
  unsigned short* lBp = &lB[tid * 8];

  f32x4 acc[4][4] = {};

  const int fr = lane & 15;          // fragment row (A) / col (B)
  const int fk = (lane >> 4) * 8;    // k chunk
  const int wm = (wave >> 1) * 64;
  const int wn = (wave & 1) * 64;

  const int nk = K >> 5;
  for (int kt = 0; kt < nk; ++kt) {
    GL_LDS16(Ag, lAp);
    GL_LDS16(Ag + 64 * ldaL, lAp + 64 * 32);
    GL_LDS16(Bg, lBp);
    GL_LDS16(Bg + 64 * ldbL, lBp + 64 * 32);
    Ag += 32; Bg += 32;
    __syncthreads();   // drains vmcnt(0): staged tile visible to all waves

    bf16x8 af[4], bfb[4];
#pragma unroll
    for (int m = 0; m < 4; ++m)
      af[m] = *(const bf16x8*)&lA[(wm + m * 16 + fr) * 32 + fk];
#pragma unroll
    for (int n = 0; n < 4; ++n)
      bfb[n] = *(const bf16x8*)&lB[(wn + n * 16 + fr) * 32 + fk];
#pragma unroll
    for (int m = 0; m < 4; ++m)
#pragma unroll
      for (int n = 0; n < 4; ++n)
        acc[m][n] = __builtin_amdgcn_mfma_f32_16x16x32_bf16(af[m], bfb[n],
                                                            acc[m][n], 0, 0, 0);
    __syncthreads();   // everyone done reading LDS before next stage
  }

  // epilogue: C/D layout col = lane&15, row = (lane>>4)*4 + i  [m89/m91]
  const int crow = (lane >> 4) * 4;
  const int ccol = lane & 15;
#pragma unroll
  for (int n = 0; n < 4; ++n) {
    const int col = n0 + wn + n * 16 + ccol;
    const float bb = bias ? bias[col] : 0.0f;
#pragma unroll
    for (int m = 0; m < 4; ++m) {
      const int rowb = m0 + wm + m * 16 + crow;
      if (OUT == 0) {
        float* C = (float*)Cout + blockIdx.z * sCz;
#pragma unroll
        for (int i = 0; i < 4; ++i)
          C[(long)(rowb + i) * ldc + col] = acc[m][n][i] + bb;
      } else if (OUT == 1) {
        unsigned short* C = (unsigned short*)Cout + blockIdx.z * sCz;
#pragma unroll
        for (int i = 0; i < 4; ++i)
          C[(long)(rowb + i) * ldc + col] = f2bf(acc[m][n][i] + bb);
      } else {
        unsigned short* C = (unsigned short*)Cout + blockIdx.z * sCz;
        ushort4 pk;
        pk.x = f2bf(acc[m][n][0] + bb);
        pk.y = f2bf(acc[m][n][1] + bb);
        pk.z = f2bf(acc[m][n][2] + bb);
        pk.w = f2bf(acc[m][n][3] + bb);
        *(ushort4*)&C[(long)col * ldc + rowb] = pk;   // 4 consecutive rows
      }
    }
  }
}

// ---------------------------------------------------------------------------
// In-place row softmax over bf16 rows of length 1024, with logit scale.
// One 256-thread block per row; 4 elements/thread.
// ---------------------------------------------------------------------------
__global__ __launch_bounds__(256)
void softmax_rows(unsigned short* __restrict__ S, float inv_scale)
{
  __shared__ float red[8];
  unsigned short* p = S + (long)blockIdx.x * 1024 + threadIdx.x * 4;
  ushort4 raw = *(const ushort4*)p;
  float v0 = bf2f(raw.x) * inv_scale;
  float v1 = bf2f(raw.y) * inv_scale;
  float v2 = bf2f(raw.z) * inv_scale;
  float v3 = bf2f(raw.w) * inv_scale;

  float mx = fmaxf(fmaxf(v0, v1), fmaxf(v2, v3));
#pragma unroll
  for (int o = 32; o >= 1; o >>= 1) mx = fmaxf(mx, __shfl_xor(mx, o));
  const int w = threadIdx.x >> 6;
  if ((threadIdx.x & 63) == 0) red[w] = mx;
  __syncthreads();
  mx = fmaxf(fmaxf(red[0], red[1]), fmaxf(red[2], red[3]));

  float e0 = __expf(v0 - mx), e1 = __expf(v1 - mx);
  float e2 = __expf(v2 - mx), e3 = __expf(v3 - mx);
  float s = (e0 + e1) + (e2 + e3);
#pragma unroll
  for (int o = 32; o >= 1; o >>= 1) s += __shfl_xor(s, o);
  if ((threadIdx.x & 63) == 0) red[4 + w] = s;
  __syncthreads();
  s = (red[4] + red[5]) + (red[6] + red[7]);
  const float inv = 1.0f / s;

  ushort4 o4;
  o4.x = f2bf(e0 * inv); o4.y = f2bf(e1 * inv);
  o4.z = f2bf(e2 * inv); o4.w = f2bf(e3 * inv);
  *(ushort4*)p = o4;
}

// ---------------------------------------------------------------------------
__global__ __launch_bounds__(256)
void cast_f32_bf16(const float* __restrict__ src, unsigned short* __restrict__ dst,
                   int n)
{
  int i = (blockIdx.x * 256 + threadIdx.x) * 4;
  const int stride = gridDim.x * 256 * 4;
  for (; i < n; i += stride) {
    float4 f = *(const float4*)(src + i);
    ushort4 o;
    o.x = f2bf(f.x); o.y = f2bf(f.y); o.z = f2bf(f.z); o.w = f2bf(f.w);
    *(ushort4*)(dst + i) = o;
  }
}

// out[i] = sum of 4 split-K partials + bias[col]; n elements, float4/thread.
__global__ __launch_bounds__(256)
void reduce4_bias(const float* __restrict__ p, const float* __restrict__ bo,
                  float* __restrict__ out, int n, long sz)
{
  int i = (blockIdx.x * 256 + threadIdx.x) * 4;
  if (i >= n) return;
  float4 a = *(const float4*)(p + i);
  float4 b = *(const float4*)(p + sz + i);
  float4 c = *(const float4*)(p + 2 * sz + i);
  float4 d = *(const float4*)(p + 3 * sz + i);
  const int col = i % 768;           // i%4==0 and 768%4==0 -> no wrap in float4
  float4 bb = *(const float4*)(bo + col);
  float4 o;
  o.x = a.x + b.x + c.x + d.x + bb.x;
  o.y = a.y + b.y + c.y + d.y + bb.y;
  o.z = a.z + b.z + c.z + d.z + bb.z;
  o.w = a.w + b.w + c.w + d.w + bb.w;
  *(float4*)(out + i) = o;
}

// ---------------------------------------------------------------------------
extern "C" void kernel_launch(void* const* d_in, const int* in_sizes, int n_in,
                              void* d_out, int out_size, void* d_ws, size_t ws_size,
                              hipStream_t stream)
{
  const float* X  = (const float*)d_in[0];
  const float* Wq = (const float*)d_in[1];
  const float* bq = (const float*)d_in[2];
  const float* Wk = (const float*)d_in[3];
  const float* bk = (const float*)d_in[4];
  const float* Wv = (const float*)d_in[5];
  const float* bv = (const float*)d_in[6];
  const float* Wo = (const float*)d_in[7];
  const float* bo = (const float*)d_in[8];

  // B=8, S=1024, D=768, H=12.  Compact workspace layout (~126 MiB):
  //   Xb   [8][1024][768]  bf16
  //   Wb   [27648][768]    bf16  (Wq|Wk|Wv row-stacked)
  //   Wob  [768][9216]     bf16
  //   bqk  [18432]         f32   (bq|bk)
  //   qkreg: 37,748,736 B region, time-shared per batch:
  //     phase 1: qk  [1024][18432] bf16
  //     phase 2: vT  [9216][1024]  bf16 (lower half)  |  Hcat_b [1024][9216]
  //              bf16 (upper half)
  //     phase 3: partials [4][1024][768] f32 (over dead vT)  |  Hcat_b
  //   Sb   [12][1024][1024] bf16
  char* ws = (char*)d_ws;
  auto alloc = [&](long bytes) {
    char* p = ws;
    ws += (bytes + 255) & ~255l;
    return p;
  };
  unsigned short* Xb    = (unsigned short*)alloc(6291456l * 2);
  unsigned short* Wb    = (unsigned short*)alloc(21233664l * 2);
  unsigned short* Wob   = (unsigned short*)alloc(7077888l * 2);
  float*          bqk   = (float*)alloc(18432l * 4);
  unsigned short* qkreg = (unsigned short*)alloc(18874368l * 2);
  unsigned short* Sb    = (unsigned short*)alloc(12582912l * 2);

  unsigned short* qk    = qkreg;                 // [1024][18432]
  unsigned short* vT    = qkreg;                 // [9216][1024]
  unsigned short* Hcat1 = qkreg + 9437184;       // [1024][9216]
  float*          part  = (float*)qkreg;         // [4][1024][768]

  cast_f32_bf16<<<1024, 256, 0, stream>>>(X,  Xb,  6291456);
  cast_f32_bf16<<<1024, 256, 0, stream>>>(Wq, Wb,            7077888);
  cast_f32_bf16<<<1024, 256, 0, stream>>>(Wk, Wb +  7077888, 7077888);
  cast_f32_bf16<<<1024, 256, 0, stream>>>(Wv, Wb + 14155776, 7077888);
  cast_f32_bf16<<<1024, 256, 0, stream>>>(Wo, Wob, 7077888);
  hipMemcpyAsync(bqk,        bq, 9216 * 4, hipMemcpyDeviceToDevice, stream);
  hipMemcpyAsync(bqk + 9216, bk, 9216 * 4, hipMemcpyDeviceToDevice, stream);

  for (int b = 0; b < 8; ++b) {
    const unsigned short* Xbb = Xb + (long)b * 786432;

    // 1) Q,K projection: [1024,768] x [18432,768]^T -> qk [1024][18432]
    gemm_bt<1><<<dim3(144, 8, 1), 256, 0, stream>>>(
        Xbb, 768, 0, Wb, 768, 0, qk, 18432, 0, bqk, 768);

    // 2) scores[h][s][t] = q[s,:] . k[t,:]   (z = head; column offsets z*768)
    gemm_bt<1><<<dim3(8, 8, 12), 256, 0, stream>>>(
        qk, 18432, 768, qk + 9216, 18432, 768, Sb, 1024, 1048576, nullptr, 768);

    // 3) softmax over t (scale 1/768^2), in place
    softmax_rows<<<12288, 256, 0, stream>>>(Sb, 1.0f / 589824.0f);

    // 4) V projection (qk now dead), transposed out: vT[(h,e)][s]
    gemm_bt<2><<<dim3(72, 8, 1), 256, 0, stream>>>(
        Xbb, 768, 0, Wb + 14155776, 768, 0, vT, 1024, 0, bv, 768);

    // 5) H[s][e] = P[s,:] . vT[e,:]  -> Hcat_b[s][h*768+e]
    gemm_bt<1><<<dim3(6, 8, 12), 256, 0, stream>>>(
        Sb, 1024, 1048576, vT, 1024, 786432, Hcat1, 9216, 768, nullptr, 1024);

    // 6) out-proj split-K (z = K-chunk of 2304): partials over dead vT
    gemm_bt<0><<<dim3(6, 8, 4), 256, 0, stream>>>(
        Hcat1, 9216, 2304, Wob, 9216, 2304, part, 768, 786432, nullptr, 2304);

    // 7) out[b*1024+s][o] = sum partials + bo
    reduce4_bias<<<768, 256, 0, stream>>>(
        part, bo, (float*)d_out + (long)b * 786432, 786432, 786432);
  }

  (void)in_sizes; (void)n_in; (void)out_size; (void)ws_size;
}

// Round 3
// 1656.492 us; speedup vs baseline: 1.1670x; 1.1670x over previous
//
#include <hip/hip_runtime.h>
#include <hip/hip_bf16.h>

typedef short bf16x8 __attribute__((ext_vector_type(8)));
typedef float f32x4 __attribute__((ext_vector_type(4)));

__device__ __forceinline__ unsigned short f2bf(float f) {
  union { float f; unsigned u; } c; c.f = f;
  unsigned u = c.u;
  return (unsigned short)((u + 0x7fffu + ((u >> 16) & 1u)) >> 16);
}
__device__ __forceinline__ float bf2f(unsigned short h) {
  union { unsigned u; float f; } c; c.u = ((unsigned)h) << 16;
  return c.f;
}

#define GL_LDS16(gp, lp)                                                        \
  __builtin_amdgcn_global_load_lds(                                             \
      (const __attribute__((address_space(1))) void*)(const void*)(gp),         \
      (__attribute__((address_space(3))) void*)(void*)(lp), 16, 0, 0)

// ---------------------------------------------------------------------------
// C[m,n] = sum_k A[m,k] * B[n,k]  (+ bias[n]), B^T layout.
// OUT==0: fp32 C[row*ldc+col]   OUT==1: bf16 C[row*ldc+col]
// OUT==2: bf16 transposed C[col*ldc+row]
//
// Pipelined structure (T2+T3+T4+T5):
//  - 4-deep circular LDS K-tile buffers (BK=32), one barrier per K-tile,
//    counted s_waitcnt vmcnt(8) in steady state (never 0 until tail).
//  - LDS tile rows are 64 B (4 x 16 B chunks); chunk XOR-swizzle
//    c' = c ^ (row&3) ^ ((row>>2)&3) makes ds_read_b128 2-way (free).
//    global_load_lds writes linearly, so the SOURCE address is pre-swizzled
//    (rule #21: inverse-swz source + linear dest + swz read).
//  - Race proof: stage(kt+2) targets buf (kt+2)%4; the slowest wave can be
//    holding reads only of tile kt-1 (distance 3 < 4 buffers). All reads of
//    a recycled buffer completed (lgkmcnt before MFMA) before barrier kt-1,
//    which precedes any wave issuing stage(kt+2). vmcnt precedes barrier in
//    program order, so after barrier kt every wave's tile-kt loads landed.
// ---------------------------------------------------------------------------
template <int BM, int BN, int WM, int WN, int OUT>
__global__ __launch_bounds__(WM * WN * 64)
void gemm_bt(const unsigned short* __restrict__ A, int lda, long sAz,
             const unsigned short* __restrict__ B, int ldb, long sBz,
             void* __restrict__ Cout, int ldc, long sCz,
             const float* __restrict__ bias, int K)
{
  constexpr int THREADS = WM * WN * 64;
  constexpr int FM = BM / WM / 16;
  constexpr int FN = BN / WN / 16;
  constexpr int TR = BM + BN;                  // A rows stacked above B rows
  static_assert(THREADS / 2 == BM && THREADS / 2 == BN, "slot mapping");
  __shared__ unsigned short lds[4 * TR * 32];

  const int tid  = threadIdx.x;
  const int lane = tid & 63;
  const int wave = tid >> 6;
  const int wn = wave % WN, wm = wave / WN;
  const int m0 = blockIdx.y * BM;
  const int n0 = blockIdx.x * BN;
  A += (long)blockIdx.z * sAz;
  B += (long)blockIdx.z * sBz;

  // staging: slot = tid + s*THREADS, row = slot>>2, phys chunk = tid&3.
  // source holds logical chunk lc = (tid&3) ^ swz(row); swz is invariant
  // across the 4 slots of a thread (row steps by THREADS/4, multiple of 16).
  const int srow = tid >> 2;
  const int swzs = (srow & 3) ^ ((srow >> 2) & 3);
  const int lc   = ((tid & 3) ^ swzs) * 8;     // element offset of 16B chunk
  const long ldaL = lda, ldbL = ldb;
  const unsigned short* gA0 = A + (long)(m0 + srow) * ldaL + lc;
  const unsigned short* gA1 = A + (long)(m0 + srow + THREADS / 4) * ldaL + lc;
  const unsigned short* gB0 = B + (long)(n0 + srow) * ldbL + lc;
  const unsigned short* gB1 = B + (long)(n0 + srow + THREADS / 4) * ldbL + lc;

  auto stage = [&](int kt) {
    unsigned short* lb = &lds[(kt & 3) * (TR * 32)];
    const long k0 = (long)kt * 32;
    GL_LDS16(gA0 + k0, &lb[(tid + 0 * THREADS) * 8]);
    GL_LDS16(gA1 + k0, &lb[(tid + 1 * THREADS) * 8]);
    GL_LDS16(gB0 + k0, &lb[(tid + 2 * THREADS) * 8]);
    GL_LDS16(gB1 + k0, &lb[(tid + 3 * THREADS) * 8]);
  };

  // fragment reads: row = base + m*16 + fr; swz(row) = (fr&3)^((fr>>2)&3)
  // (bases are multiples of 16, so row mod 16 == fr mod 16).
  const int fr   = lane & 15;
  const int fkx  = lane >> 4;
  const int swzr = (fr & 3) ^ ((fr >> 2) & 3);
  const int pc   = (fkx ^ swzr) * 8;           // physical chunk elem offset
  const int aRowBase = wm * (BM / WM);
  const int bRowBase = BM + wn * (BN / WN);

  f32x4 acc[FM][FN] = {};
  const int nk = K >> 5;

  stage(0);
  if (nk > 1) stage(1);

  for (int kt = 0; kt < nk; ++kt) {
    if (kt + 2 < nk) stage(kt + 2);
    if (kt + 2 < nk)      asm volatile("s_waitcnt vmcnt(8)" ::: "memory");
    else if (kt + 1 < nk) asm volatile("s_waitcnt vmcnt(4)" ::: "memory");
    else                  asm volatile("s_waitcnt vmcnt(0)" ::: "memory");
    __builtin_amdgcn_sched_barrier(0);
    __builtin_amdgcn_s_barrier();
    __builtin_amdgcn_sched_barrier(0);

    const unsigned short* lb = &lds[(kt & 3) * (TR * 32)];
    bf16x8 af[FM], bfr[FN];
#pragma unroll
    for (int m = 0; m < FM; ++m)
      af[m] = *(const bf16x8*)&lb[(aRowBase + m * 16 + fr) * 32 + pc];
#pragma unroll
    for (int n = 0; n < FN; ++n)
      bfr[n] = *(const bf16x8*)&lb[(bRowBase + n * 16 + fr) * 32 + pc];

    __builtin_amdgcn_s_setprio(1);
#pragma unroll
    for (int m = 0; m < FM; ++m)
#pragma unroll
      for (int n = 0; n < FN; ++n)
        acc[m][n] = __builtin_amdgcn_mfma_f32_16x16x32_bf16(af[m], bfr[n],
                                                            acc[m][n], 0, 0, 0);
    __builtin_amdgcn_s_setprio(0);
  }

  // epilogue: C/D layout col = lane&15, row = (lane>>4)*4 + i  [m89/m91]
  const int crow = (lane >> 4) * 4;
  const int ccol = lane & 15;
#pragma unroll
  for (int n = 0; n < FN; ++n) {
    const int col = n0 + wn * (BN / WN) + n * 16 + ccol;
    const float bb = bias ? bias[col] : 0.0f;
#pragma unroll
    for (int m = 0; m < FM; ++m) {
      const int rowb = m0 + aRowBase + m * 16 + crow;
      if (OUT == 0) {
        float* C = (float*)Cout + blockIdx.z * sCz;
#pragma unroll
        for (int i = 0; i < 4; ++i)
          C[(long)(rowb + i) * ldc + col] = acc[m][n][i] + bb;
      } else if (OUT == 1) {
        unsigned short* C = (unsigned short*)Cout + blockIdx.z * sCz;
#pragma unroll
        for (int i = 0; i < 4; ++i)
          C[(long)(rowb + i) * ldc + col] = f2bf(acc[m][n][i] + bb);
      } else {
        unsigned short* C = (unsigned short*)Cout + blockIdx.z * sCz;
        ushort4 pk;
        pk.x = f2bf(acc[m][n][0] + bb);
        pk.y = f2bf(acc[m][n][1] + bb);
        pk.z = f2bf(acc[m][n][2] + bb);
        pk.w = f2bf(acc[m][n][3] + bb);
        *(ushort4*)&C[(long)col * ldc + rowb] = pk;   // 4 consecutive rows
      }
    }
  }
}

// ---------------------------------------------------------------------------
// In-place row softmax over bf16 rows of length 1024, with logit scale.
// ---------------------------------------------------------------------------
__global__ __launch_bounds__(256)
void softmax_rows(unsigned short* __restrict__ S, float inv_scale)
{
  __shared__ float red[8];
  unsigned short* p = S + (long)blockIdx.x * 1024 + threadIdx.x * 4;
  ushort4 raw = *(const ushort4*)p;
  float v0 = bf2f(raw.x) * inv_scale;
  float v1 = bf2f(raw.y) * inv_scale;
  float v2 = bf2f(raw.z) * inv_scale;
  float v3 = bf2f(raw.w) * inv_scale;

  float mx = fmaxf(fmaxf(v0, v1), fmaxf(v2, v3));
#pragma unroll
  for (int o = 32; o >= 1; o >>= 1) mx = fmaxf(mx, __shfl_xor(mx, o));
  const int w = threadIdx.x >> 6;
  if ((threadIdx.x & 63) == 0) red[w] = mx;
  __syncthreads();
  mx = fmaxf(fmaxf(red[0], red[1]), fmaxf(red[2], red[3]));

  float e0 = __expf(v0 - mx), e1 = __expf(v1 - mx);
  float e2 = __expf(v2 - mx), e3 = __expf(v3 - mx);
  float s = (e0 + e1) + (e2 + e3);
#pragma unroll
  for (int o = 32; o >= 1; o >>= 1) s += __shfl_xor(s, o);
  if ((threadIdx.x & 63) == 0) red[4 + w] = s;
  __syncthreads();
  s = (red[4] + red[5]) + (red[6] + red[7]);
  const float inv = 1.0f / s;

  ushort4 o4;
  o4.x = f2bf(e0 * inv); o4.y = f2bf(e1 * inv);
  o4.z = f2bf(e2 * inv); o4.w = f2bf(e3 * inv);
  *(ushort4*)p = o4;
}

// ---------------------------------------------------------------------------
__global__ __launch_bounds__(256)
void cast_f32_bf16(const float* __restrict__ src, unsigned short* __restrict__ dst,
                   int n)
{
  int i = (blockIdx.x * 256 + threadIdx.x) * 4;
  const int stride = gridDim.x * 256 * 4;
  for (; i < n; i += stride) {
    float4 f = *(const float4*)(src + i);
    ushort4 o;
    o.x = f2bf(f.x); o.y = f2bf(f.y); o.z = f2bf(f.z); o.w = f2bf(f.w);
    *(ushort4*)(dst + i) = o;
  }
}

// out[i] = sum of 4 split-K partials + bias[col]; n elements, float4/thread.
__global__ __launch_bounds__(256)
void reduce4_bias(const float* __restrict__ p, const float* __restrict__ bo,
                  float* __restrict__ out, int n, long sz)
{
  int i = (blockIdx.x * 256 + threadIdx.x) * 4;
  if (i >= n) return;
  float4 a = *(const float4*)(p + i);
  float4 b = *(const float4*)(p + sz + i);
  float4 c = *(const float4*)(p + 2 * sz + i);
  float4 d = *(const float4*)(p + 3 * sz + i);
  const int col = i % 768;
  float4 bb = *(const float4*)(bo + col);
  float4 o;
  o.x = a.x + b.x + c.x + d.x + bb.x;
  o.y = a.y + b.y + c.y + d.y + bb.y;
  o.z = a.z + b.z + c.z + d.z + bb.z;
  o.w = a.w + b.w + c.w + d.w + bb.w;
  *(float4*)(out + i) = o;
}

// ---------------------------------------------------------------------------
extern "C" void kernel_launch(void* const* d_in, const int* in_sizes, int n_in,
                              void* d_out, int out_size, void* d_ws, size_t ws_size,
                              hipStream_t stream)
{
  const float* X  = (const float*)d_in[0];
  const float* Wq = (const float*)d_in[1];
  const float* bq = (const float*)d_in[2];
  const float* Wk = (const float*)d_in[3];
  const float* bk = (const float*)d_in[4];
  const float* Wv = (const float*)d_in[5];
  const float* bv = (const float*)d_in[6];
  const float* Wo = (const float*)d_in[7];
  const float* bo = (const float*)d_in[8];

  // B=8, S=1024, D=768, H=12.  Compact workspace (~126 MiB), per-batch
  // time-shared qkreg region (qk -> vT|Hcat -> partials|Hcat).
  char* ws = (char*)d_ws;
  auto alloc = [&](long bytes) {
    char* p = ws;
    ws += (bytes + 255) & ~255l;
    return p;
  };
  unsigned short* Xb    = (unsigned short*)alloc(6291456l * 2);
  unsigned short* Wb    = (unsigned short*)alloc(21233664l * 2);
  unsigned short* Wob   = (unsigned short*)alloc(7077888l * 2);
  float*          bqk   = (float*)alloc(18432l * 4);
  unsigned short* qkreg = (unsigned short*)alloc(18874368l * 2);
  unsigned short* Sb    = (unsigned short*)alloc(12582912l * 2);

  unsigned short* qk    = qkreg;                 // [1024][18432]
  unsigned short* vT    = qkreg;                 // [9216][1024]
  unsigned short* Hcat1 = qkreg + 9437184;       // [1024][9216]
  float*          part  = (float*)qkreg;         // [4][1024][768]

  cast_f32_bf16<<<1024, 256, 0, stream>>>(X,  Xb,  6291456);
  cast_f32_bf16<<<1024, 256, 0, stream>>>(Wq, Wb,            7077888);
  cast_f32_bf16<<<1024, 256, 0, stream>>>(Wk, Wb +  7077888, 7077888);
  cast_f32_bf16<<<1024, 256, 0, stream>>>(Wv, Wb + 14155776, 7077888);
  cast_f32_bf16<<<1024, 256, 0, stream>>>(Wo, Wob, 7077888);
  hipMemcpyAsync(bqk,        bq, 9216 * 4, hipMemcpyDeviceToDevice, stream);
  hipMemcpyAsync(bqk + 9216, bk, 9216 * 4, hipMemcpyDeviceToDevice, stream);

  for (int b = 0; b < 8; ++b) {
    const unsigned short* Xbb = Xb + (long)b * 786432;

    // 1) Q,K projection: [1024,768] x [18432,768]^T -> qk [1024][18432]
    gemm_bt<128, 128, 2, 2, 1><<<dim3(144, 8, 1), 256, 0, stream>>>(
        Xbb, 768, 0, Wb, 768, 0, qk, 18432, 0, bqk, 768);

    // 2) scores[h][s][t] = q[s,:] . k[t,:]   (z = head; column offsets z*768)
    gemm_bt<128, 128, 2, 2, 1><<<dim3(8, 8, 12), 256, 0, stream>>>(
        qk, 18432, 768, qk + 9216, 18432, 768, Sb, 1024, 1048576, nullptr, 768);

    // 3) softmax over t (scale 1/768^2), in place
    softmax_rows<<<12288, 256, 0, stream>>>(Sb, 1.0f / 589824.0f);

    // 4) V projection (qk now dead), transposed out: vT[(h,e)][s]
    gemm_bt<128, 128, 2, 2, 2><<<dim3(72, 8, 1), 256, 0, stream>>>(
        Xbb, 768, 0, Wb + 14155776, 768, 0, vT, 1024, 0, bv, 768);

    // 5) H[s][e] = P[s,:] . vT[e,:]  -> Hcat_b[s][h*768+e]
    gemm_bt<128, 128, 2, 2, 1><<<dim3(6, 8, 12), 256, 0, stream>>>(
        Sb, 1024, 1048576, vT, 1024, 786432, Hcat1, 9216, 768, nullptr, 1024);

    // 6) out-proj split-K (z = K-chunk of 2304): partials over dead vT
    gemm_bt<128, 128, 2, 2, 0><<<dim3(6, 8, 4), 256, 0, stream>>>(
        Hcat1, 9216, 2304, Wob, 9216, 2304, part, 768, 786432, nullptr, 2304);

    // 7) out[b*1024+s][o] = sum partials + bo
    reduce4_bias<<<768, 256, 0, stream>>>(
        part, bo, (float*)d_out + (long)b * 786432, 786432, 786432);
  }

  (void)in_sizes; (void)n_in; (void)out_size; (void)ws_size;
}